// Round 5
// baseline (234.543 us; speedup 1.0000x reference)
//
#include <hip/hip_runtime.h>

// B=2, D=64, N=512, H=256, OUT=64
// mid[b] = sum_{c,i} relu( relu(hi[b,i]+hc[b,c]+b1) @ w2 + b2 ) @ w3 + N^2*b3
// out = relu(mid @ w4 + b4) @ w5 + b5

using f32x16  = __attribute__((ext_vector_type(16))) float;
using short8  = __attribute__((ext_vector_type(8))) short;
using float2v = __attribute__((ext_vector_type(2))) float;

__device__ __forceinline__ short f2bf(float f) {
    unsigned u = __float_as_uint(f);
    unsigned r = u + 0x7FFFu + ((u >> 16) & 1u);   // RNE
    return (short)(r >> 16);
}

// ---- prep (merged): blocks [0,1024): hi/hcb; blocks [1024,1280): w2t transpose
__global__ __launch_bounds__(256) void prep(const float* __restrict__ in,
                                            const float* __restrict__ w1,
                                            const float* __restrict__ b1,
                                            const float* __restrict__ w2,
                                            float* __restrict__ hi,
                                            float* __restrict__ hcb,
                                            short* __restrict__ w2t) {
    int tid = threadIdx.x;
    int bidx = blockIdx.x;
    if (bidx < 1024) {
        int b = bidx >> 9, n = bidx & 511;
        __shared__ float xs[64];
        if (tid < 64) xs[tid] = in[(size_t)(b * 64 + tid) * 512 + n];
        __syncthreads();
        float a0 = 0.f, a1 = 0.f;
#pragma unroll 8
        for (int d = 0; d < 64; ++d) {
            float xv = xs[d];
            a0 += xv * w1[d * 256 + tid];
            a1 += xv * w1[(64 + d) * 256 + tid];
        }
        size_t o = (size_t)(b * 512 + n) * 256 + tid;
        hi[o]  = a0;
        hcb[o] = a1 + b1[tid];
    } else {
        int idx = (bidx - 1024) * 256 + tid;
        int n = idx & 255, k = idx >> 8;
        w2t[n * 256 + k] = f2bf(w2[k * 256 + n]);
    }
}

// ---- big (v5): exact R1 structure + b2-fold + setprio + barrier-before-epilogue
__global__ __launch_bounds__(256, 2) void big(const float* __restrict__ hi,
                                              const float* __restrict__ hcb,
                                              const short* __restrict__ w2t,
                                              const float* __restrict__ b2,
                                              float* __restrict__ partials) {
    __shared__ __align__(16) unsigned tA[2][64 * 128];   // 2 x 32 KB

    const int tid = threadIdx.x;
    const int bid = blockIdx.x;                 // [0,512)
    const int b   = bid >> 8, rem = bid & 255;
    const int cc  = rem >> 2, icg = rem & 3;

    const float* __restrict__ hib  = hi  + (size_t)b * (512 * 256);
    const float* __restrict__ hcbb = hcb + (size_t)b * (512 * 256);

    const int cp   = tid & 127, half = tid >> 7;   // A-gen mapping
    const int lane = tid & 63,  wid  = tid >> 6;   // MFMA mapping
    const int h = lane >> 5, l31 = lane & 31, l7 = lane & 7;
    const int colbase = wid * 64;

    float2v cv2[4];
#pragma unroll
    for (int j = 0; j < 4; ++j)
        cv2[j] = *reinterpret_cast<const float2v*>(
            &hcbb[(size_t)(cc * 8 + half * 4 + j) * 256 + 2 * cp]);

    // persistent B fragments: 64 cols x K=256 bf16 per wave = 128 VGPRs
    short8 bfr[2][16];
    const short8* w2v = reinterpret_cast<const short8*>(w2t);
#pragma unroll
    for (int cf = 0; cf < 2; ++cf)
#pragma unroll
        for (int kk = 0; kk < 16; ++kk)
            bfr[cf][kk] = w2v[(size_t)(colbase + cf * 32 + l31) * 32 + kk * 2 + h];

    const float b2v0 = b2[colbase + l31];
    const float b2v1 = b2[colbase + 32 + l31];
    float psum0 = 0.f, psum1 = 0.f;

    const int cbase = cp >> 2, woff = cp & 3;

    auto gen = [&](int ic, unsigned* __restrict__ buf) {
        float2v hv2[8];
#pragma unroll
        for (int j = 0; j < 8; ++j)
            hv2[j] = *reinterpret_cast<const float2v*>(
                &hib[(size_t)(ic * 8 + j) * 256 + 2 * cp]);
#pragma unroll
        for (int p = 0; p < 32; ++p) {
            float ax = hv2[p & 7][0] + cv2[p >> 3][0];
            float ay = hv2[p & 7][1] + cv2[p >> 3][1];
            ax = fmaxf(ax, 0.f);
            ay = fmaxf(ay, 0.f);
            unsigned pk;
            asm("v_cvt_pk_bf16_f32 %0, %1, %2" : "=v"(pk) : "v"(ax), "v"(ay));
            buf[(half * 32 + p) * 128 + (((cbase ^ (p & 7)) << 2) + woff)] = pk;
        }
    };

    gen(icg * 16, tA[0]);
    __syncthreads();

#pragma unroll 2
    for (int t = 0; t < 16; ++t) {
        const int cur = t & 1;
        if (t < 15) gen(icg * 16 + t + 1, tA[cur ^ 1]);

        const short8* tAv = reinterpret_cast<const short8*>(tA[cur]);
        f32x16 acc00, acc01, acc10, acc11;
#pragma unroll
        for (int e = 0; e < 16; ++e) {
            acc00[e] = b2v0; acc01[e] = b2v1;
            acc10[e] = b2v0; acc11[e] = b2v1;
        }
#pragma unroll
        for (int kk = 0; kk < 16; ++kk) {
            const int sc = (kk * 2 + h) ^ l7;
            short8 a0 = tAv[l31 * 32 + sc];
            short8 a1 = tAv[(32 + l31) * 32 + sc];
            __builtin_amdgcn_s_setprio(1);
            acc00 = __builtin_amdgcn_mfma_f32_32x32x16_bf16(a0, bfr[0][kk], acc00, 0, 0, 0);
            acc01 = __builtin_amdgcn_mfma_f32_32x32x16_bf16(a0, bfr[1][kk], acc01, 0, 0, 0);
            acc10 = __builtin_amdgcn_mfma_f32_32x32x16_bf16(a1, bfr[0][kk], acc10, 0, 0, 0);
            acc11 = __builtin_amdgcn_mfma_f32_32x32x16_bf16(a1, bfr[1][kk], acc11, 0, 0, 0);
            __builtin_amdgcn_s_setprio(0);
        }
        __syncthreads();

        float s0 = 0.f, s1 = 0.f;
#pragma unroll
        for (int e = 0; e < 16; ++e) {
            s0 += fmaxf(acc00[e], 0.f);
            s0 += fmaxf(acc10[e], 0.f);
            s1 += fmaxf(acc01[e], 0.f);
            s1 += fmaxf(acc11[e], 0.f);
        }
        psum0 += s0;
        psum1 += s1;
    }

    psum0 += __shfl_xor(psum0, 32);
    psum1 += __shfl_xor(psum1, 32);
    if (h == 0) {
        partials[(size_t)bid * 256 + colbase + l31]      = psum0;
        partials[(size_t)bid * 256 + colbase + 32 + l31] = psum1;
    }
}

// ---- probe_mfma: big minus in-loop gen (MFMA+ds_read+barrier+epilogue cost only)
__global__ __launch_bounds__(256, 2) void probe_mfma(const float* __restrict__ hi,
                                                     const float* __restrict__ hcb,
                                                     const short* __restrict__ w2t,
                                                     const float* __restrict__ b2,
                                                     float* __restrict__ scratch) {
    __shared__ __align__(16) unsigned tA[2][64 * 128];

    const int tid = threadIdx.x;
    const int bid = blockIdx.x;
    const int b   = bid >> 8, rem = bid & 255;
    const int cc  = rem >> 2, icg = rem & 3;

    const float* __restrict__ hib  = hi  + (size_t)b * (512 * 256);
    const float* __restrict__ hcbb = hcb + (size_t)b * (512 * 256);

    const int cp   = tid & 127, half = tid >> 7;
    const int lane = tid & 63,  wid  = tid >> 6;
    const int h = lane >> 5, l31 = lane & 31, l7 = lane & 7;
    const int colbase = wid * 64;

    float2v cv2[4];
#pragma unroll
    for (int j = 0; j < 4; ++j)
        cv2[j] = *reinterpret_cast<const float2v*>(
            &hcbb[(size_t)(cc * 8 + half * 4 + j) * 256 + 2 * cp]);

    short8 bfr[2][16];
    const short8* w2v = reinterpret_cast<const short8*>(w2t);
#pragma unroll
    for (int cf = 0; cf < 2; ++cf)
#pragma unroll
        for (int kk = 0; kk < 16; ++kk)
            bfr[cf][kk] = w2v[(size_t)(colbase + cf * 32 + l31) * 32 + kk * 2 + h];

    const float b2v0 = b2[colbase + l31];
    const float b2v1 = b2[colbase + 32 + l31];
    float psum0 = 0.f, psum1 = 0.f;

    const int cbase = cp >> 2, woff = cp & 3;

    auto gen = [&](int ic, unsigned* __restrict__ buf) {
        float2v hv2[8];
#pragma unroll
        for (int j = 0; j < 8; ++j)
            hv2[j] = *reinterpret_cast<const float2v*>(
                &hib[(size_t)(ic * 8 + j) * 256 + 2 * cp]);
#pragma unroll
        for (int p = 0; p < 32; ++p) {
            float ax = hv2[p & 7][0] + cv2[p >> 3][0];
            float ay = hv2[p & 7][1] + cv2[p >> 3][1];
            ax = fmaxf(ax, 0.f);
            ay = fmaxf(ay, 0.f);
            unsigned pk;
            asm("v_cvt_pk_bf16_f32 %0, %1, %2" : "=v"(pk) : "v"(ax), "v"(ay));
            buf[(half * 32 + p) * 128 + (((cbase ^ (p & 7)) << 2) + woff)] = pk;
        }
    };

    gen(icg * 16, tA[0]);
    gen(icg * 16 + 1, tA[1]);
    __syncthreads();

#pragma unroll 2
    for (int t = 0; t < 16; ++t) {
        const int cur = t & 1;
        const short8* tAv = reinterpret_cast<const short8*>(tA[cur]);
        f32x16 acc00, acc01, acc10, acc11;
#pragma unroll
        for (int e = 0; e < 16; ++e) {
            acc00[e] = b2v0; acc01[e] = b2v1;
            acc10[e] = b2v0; acc11[e] = b2v1;
        }
#pragma unroll
        for (int kk = 0; kk < 16; ++kk) {
            const int sc = (kk * 2 + h) ^ l7;
            short8 a0 = tAv[l31 * 32 + sc];
            short8 a1 = tAv[(32 + l31) * 32 + sc];
            __builtin_amdgcn_s_setprio(1);
            acc00 = __builtin_amdgcn_mfma_f32_32x32x16_bf16(a0, bfr[0][kk], acc00, 0, 0, 0);
            acc01 = __builtin_amdgcn_mfma_f32_32x32x16_bf16(a0, bfr[1][kk], acc01, 0, 0, 0);
            acc10 = __builtin_amdgcn_mfma_f32_32x32x16_bf16(a1, bfr[0][kk], acc10, 0, 0, 0);
            acc11 = __builtin_amdgcn_mfma_f32_32x32x16_bf16(a1, bfr[1][kk], acc11, 0, 0, 0);
            __builtin_amdgcn_s_setprio(0);
        }
        __syncthreads();

        float s0 = 0.f, s1 = 0.f;
#pragma unroll
        for (int e = 0; e < 16; ++e) {
            s0 += fmaxf(acc00[e], 0.f);
            s0 += fmaxf(acc10[e], 0.f);
            s1 += fmaxf(acc01[e], 0.f);
            s1 += fmaxf(acc11[e], 0.f);
        }
        psum0 += s0;
        psum1 += s1;
    }

    psum0 += __shfl_xor(psum0, 32);
    psum1 += __shfl_xor(psum1, 32);
    if (h == 0) {
        scratch[(size_t)bid * 256 + colbase + l31]      = psum0;
        scratch[(size_t)bid * 256 + colbase + 32 + l31] = psum1;
    }
}

// ---- probe_gen: big minus MFMA (global-load + gen-VALU + ds_write + barrier cost only)
__global__ __launch_bounds__(256, 2) void probe_gen(const float* __restrict__ hi,
                                                    const float* __restrict__ hcb,
                                                    unsigned* __restrict__ scratch) {
    __shared__ __align__(16) unsigned tA[2][64 * 128];

    const int tid = threadIdx.x;
    const int bid = blockIdx.x;
    const int b   = bid >> 8, rem = bid & 255;
    const int cc  = rem >> 2, icg = rem & 3;

    const float* __restrict__ hib  = hi  + (size_t)b * (512 * 256);
    const float* __restrict__ hcbb = hcb + (size_t)b * (512 * 256);

    const int cp   = tid & 127, half = tid >> 7;

    float2v cv2[4];
#pragma unroll
    for (int j = 0; j < 4; ++j)
        cv2[j] = *reinterpret_cast<const float2v*>(
            &hcbb[(size_t)(cc * 8 + half * 4 + j) * 256 + 2 * cp]);

    const int cbase = cp >> 2, woff = cp & 3;

    auto gen = [&](int ic, unsigned* __restrict__ buf) {
        float2v hv2[8];
#pragma unroll
        for (int j = 0; j < 8; ++j)
            hv2[j] = *reinterpret_cast<const float2v*>(
                &hib[(size_t)(ic * 8 + j) * 256 + 2 * cp]);
#pragma unroll
        for (int p = 0; p < 32; ++p) {
            float ax = hv2[p & 7][0] + cv2[p >> 3][0];
            float ay = hv2[p & 7][1] + cv2[p >> 3][1];
            ax = fmaxf(ax, 0.f);
            ay = fmaxf(ay, 0.f);
            unsigned pk;
            asm("v_cvt_pk_bf16_f32 %0, %1, %2" : "=v"(pk) : "v"(ax), "v"(ay));
            buf[(half * 32 + p) * 128 + (((cbase ^ (p & 7)) << 2) + woff)] = pk;
        }
    };

    for (int t = 0; t < 16; ++t) {
        gen(icg * 16 + t, tA[t & 1]);
        __syncthreads();
    }

    // keep LDS writes alive
    scratch[(size_t)bid * 256 + tid] = tA[0][tid] ^ tA[1][tid + 256];
}

// ---- final tail: both batches in parallel (512 threads)
__global__ __launch_bounds__(512) void finalK(const float* __restrict__ partials,
                                              const float* __restrict__ w3,
                                              const float* __restrict__ b3,
                                              const float* __restrict__ w4,
                                              const float* __restrict__ b4,
                                              const float* __restrict__ w5,
                                              const float* __restrict__ b5,
                                              float* __restrict__ out) {
    __shared__ float su[2][256], mid[2][256], o[2][256];
    int tid = threadIdx.x;
    int b = tid >> 8, col = tid & 255;
    const float* pb = partials + (size_t)b * 256 * 256;
    float s = 0.f;
#pragma unroll 8
    for (int r = 0; r < 256; ++r) s += pb[(size_t)r * 256 + col];
    su[b][col] = s;
    __syncthreads();
    float m = 262144.0f * b3[col];
    for (int k = 0; k < 256; ++k) m += su[b][k] * w3[k * 256 + col];
    mid[b][col] = m;
    __syncthreads();
    float ov = b4[col];
    for (int k = 0; k < 256; ++k) ov += mid[b][k] * w4[k * 256 + col];
    o[b][col] = fmaxf(ov, 0.f);
    __syncthreads();
    if (col < 64) {
        float r = b5[col];
        for (int k = 0; k < 256; ++k) r += o[b][k] * w5[k * 64 + col];
        out[b * 64 + col] = r;
    }
}

extern "C" void kernel_launch(void* const* d_in, const int* in_sizes, int n_in,
                              void* d_out, int out_size, void* d_ws, size_t ws_size,
                              hipStream_t stream) {
    const float* in = (const float*)d_in[0];
    const float* w1 = (const float*)d_in[1];
    const float* b1 = (const float*)d_in[2];
    const float* w2 = (const float*)d_in[3];
    const float* b2 = (const float*)d_in[4];
    const float* w3 = (const float*)d_in[5];
    const float* b3 = (const float*)d_in[6];
    const float* w4 = (const float*)d_in[7];
    const float* b4 = (const float*)d_in[8];
    const float* w5 = (const float*)d_in[9];
    const float* b5 = (const float*)d_in[10];
    float* out = (float*)d_out;

    char* ws = (char*)d_ws;
    float* hi        = (float*)(ws);                                   // 1 MB
    float* hcb       = (float*)(ws + (1u << 20));                      // 1 MB
    short* w2t       = (short*)(ws + (2u << 20));                      // 128 KB
    float* partials  = (float*)(ws + (2u << 20) + (1u << 18));         // 512 KB
    float* pscratchA = (float*)(ws + (4u << 20));                      // 512 KB (probe)
    unsigned* pscratchB = (unsigned*)(ws + (5u << 20));                // 512 KB (probe)

    prep<<<1280, 256, 0, stream>>>(in, w1, b1, w2, hi, hcb, w2t);
    big<<<512, 256, 0, stream>>>(hi, hcb, w2t, b2, partials);
    probe_mfma<<<512, 256, 0, stream>>>(hi, hcb, w2t, b2, pscratchA);
    probe_gen<<<512, 256, 0, stream>>>(hi, hcb, pscratchB);
    finalK<<<1, 512, 0, stream>>>(partials, w3, b3, w4, b4, w5, b5, out);
}

// Round 6
// 183.912 us; speedup vs baseline: 1.2753x; 1.2753x over previous
//
#include <hip/hip_runtime.h>

// B=2, D=64, N=512, H=256, OUT=64
// mid[b] = sum_{c,i} relu( relu(hi[b,i,:]+hcb[b,c,:]) @ w2 + b2 ) @ w3 + N^2*b3
// out = relu(mid @ w4 + b4) @ w5 + b5
//
// big: B(w2^T col-half, fragment-ordered) in LDS (64KB, linear ds_read_b128, no
// conflicts, staged once); A generated per-lane straight into MFMA fragment regs
// (8c x 8i wave tile). No barriers in the main loop; waves desync freely.

using f32x16  = __attribute__((ext_vector_type(16))) float;
using short8  = __attribute__((ext_vector_type(8))) short;
using float4v = __attribute__((ext_vector_type(4))) float;

__device__ __forceinline__ short f2bf(float f) {
    unsigned u = __float_as_uint(f);
    unsigned r = u + 0x7FFFu + ((u >> 16) & 1u);   // RNE
    return (short)(r >> 16);
}

// relu + pack 8 f32 -> short8 (bf16)
__device__ __forceinline__ short8 relu_pack8(float4v lo, float4v hi4) {
#pragma unroll
    for (int e = 0; e < 4; ++e) {
        lo[e]  = fmaxf(lo[e], 0.f);
        hi4[e] = fmaxf(hi4[e], 0.f);
    }
    union { short8 s; unsigned u[4]; } r;
    asm("v_cvt_pk_bf16_f32 %0, %1, %2" : "=v"(r.u[0]) : "v"(lo[0]),  "v"(lo[1]));
    asm("v_cvt_pk_bf16_f32 %0, %1, %2" : "=v"(r.u[1]) : "v"(lo[2]),  "v"(lo[3]));
    asm("v_cvt_pk_bf16_f32 %0, %1, %2" : "=v"(r.u[2]) : "v"(hi4[0]), "v"(hi4[1]));
    asm("v_cvt_pk_bf16_f32 %0, %1, %2" : "=v"(r.u[3]) : "v"(hi4[2]), "v"(hi4[3]));
    return r.s;
}

// ---- prep: blocks [0,1024): hi/hcb; blocks [1024,1280): fragment-ordered w2
__global__ __launch_bounds__(256) void prep(const float* __restrict__ in,
                                            const float* __restrict__ w1,
                                            const float* __restrict__ b1,
                                            const float* __restrict__ w2,
                                            float* __restrict__ hi,
                                            float* __restrict__ hcb,
                                            short* __restrict__ bfrag) {
    int tid = threadIdx.x;
    int bidx = blockIdx.x;
    if (bidx < 1024) {
        int b = bidx >> 9, n = bidx & 511;
        __shared__ float xs[64];
        if (tid < 64) xs[tid] = in[(size_t)(b * 64 + tid) * 512 + n];
        __syncthreads();
        float a0 = 0.f, a1 = 0.f;
#pragma unroll 8
        for (int d = 0; d < 64; ++d) {
            float xv = xs[d];
            a0 += xv * w1[d * 256 + tid];
            a1 += xv * w1[(64 + d) * 256 + tid];
        }
        size_t o = (size_t)(b * 512 + n) * 256 + tid;
        hi[o]  = a0;
        hcb[o] = a1 + b1[tid];
    } else {
        // fragment-ordered B: off = (((ch*4+n)*16+kk)*64 + h*32+col)*8 + j
        // holding bf16(w2[k][ncol]) with k=16kk+8h+j, ncol=ch*128+n*32+col
        int idx = (bidx - 1024) * 256 + tid;        // [0, 65536)
        int k = idx >> 8, ncol = idx & 255;
        int ch = ncol >> 7, n = (ncol >> 5) & 3, col = ncol & 31;
        int kk = k >> 4, h = (k >> 3) & 1, j = k & 7;
        int off = ((((ch * 4 + n) * 16 + kk) * 64) + h * 32 + col) * 8 + j;
        bfrag[off] = f2bf(w2[k * 256 + ncol]);
    }
}

// ---- big (v6): 1024 blocks x 4 jobs. Block: (b, colhalf ch, ct); wave w owns
// c-octet ct*32+w*8; job t covers i-octet ig*4+t. Barrier-free main loop.
__global__ __launch_bounds__(256, 2) void big(const float* __restrict__ hi_,
                                              const float* __restrict__ hcb_,
                                              const short8* __restrict__ bfrag,
                                              const float* __restrict__ b2,
                                              float* __restrict__ partials) {
    __shared__ __align__(16) short8 Blds[4096];   // [n][kk][lane] = 64 KB

    const int tid = threadIdx.x;
    const int j = blockIdx.x;                     // [0,1024)
    const int b = j >> 9, ch = (j >> 8) & 1, ct = (j >> 4) & 15, ig = j & 15;

    // stage B col-half (linear, coalesced)
    const short8* __restrict__ bsrc = bfrag + (size_t)ch * 4096;
#pragma unroll
    for (int q = 0; q < 16; ++q) Blds[q * 256 + tid] = bsrc[q * 256 + tid];
    __syncthreads();

    const int lane = tid & 63, w = tid >> 6;
    const int col = lane & 31, h = lane >> 5;
    const int cp = (lane & 31) >> 3;   // c' (0..3); row and row+32 differ by +4
    const int ip = lane & 7;           // i'

    const float* __restrict__ hcb0 = hcb_ + (size_t)b * 131072
                                   + (size_t)(ct * 32 + w * 8 + cp) * 256 + 8 * h;
    const float* __restrict__ hcb1 = hcb0 + 4 * 256;
    const float* __restrict__ hib  = hi_ + (size_t)b * 131072
                                   + (size_t)(ig * 32 + ip) * 256 + 8 * h;

    float b2v[4];
#pragma unroll
    for (int n = 0; n < 4; ++n) b2v[n] = b2[ch * 128 + n * 32 + col];
    float psum[4] = {0.f, 0.f, 0.f, 0.f};

#pragma unroll 1
    for (int t = 0; t < 4; ++t) {
        const float* __restrict__ hirow = hib + t * 2048;

        // generate A fragments in registers: rows r=c'*8+i' (a0) and r+32 (a1)
        short8 a0[16], a1[16];
#pragma unroll
        for (int kk = 0; kk < 16; ++kk) {
            float4v x0  = *reinterpret_cast<const float4v*>(hirow + 16 * kk);
            float4v x1  = *reinterpret_cast<const float4v*>(hirow + 16 * kk + 4);
            float4v c00 = *reinterpret_cast<const float4v*>(hcb0 + 16 * kk);
            float4v c01 = *reinterpret_cast<const float4v*>(hcb0 + 16 * kk + 4);
            float4v c10 = *reinterpret_cast<const float4v*>(hcb1 + 16 * kk);
            float4v c11 = *reinterpret_cast<const float4v*>(hcb1 + 16 * kk + 4);
            a0[kk] = relu_pack8(x0 + c00, x1 + c01);
            a1[kk] = relu_pack8(x0 + c10, x1 + c11);
        }

        // 4 col-blocks of 32; acc freed after each (row-sum epilogue)
#pragma unroll
        for (int n = 0; n < 4; ++n) {
            f32x16 A0, A1;
#pragma unroll
            for (int e = 0; e < 16; ++e) { A0[e] = b2v[n]; A1[e] = b2v[n]; }
            const short8* __restrict__ bl = Blds + n * 1024 + lane;
            __builtin_amdgcn_s_setprio(1);
#pragma unroll
            for (int kk = 0; kk < 16; ++kk) {
                short8 bf = bl[kk * 64];
                A0 = __builtin_amdgcn_mfma_f32_32x32x16_bf16(a0[kk], bf, A0, 0, 0, 0);
                A1 = __builtin_amdgcn_mfma_f32_32x32x16_bf16(a1[kk], bf, A1, 0, 0, 0);
            }
            __builtin_amdgcn_s_setprio(0);
            float s = 0.f;
#pragma unroll
            for (int e = 0; e < 16; ++e)
                s += fmaxf(A0[e], 0.f) + fmaxf(A1[e], 0.f);
            psum[n] += s;
        }
    }

#pragma unroll
    for (int n = 0; n < 4; ++n) psum[n] += __shfl_xor(psum[n], 32);
    if (h == 0) {
        float* prow = partials + ((size_t)j * 4 + w) * 128;
#pragma unroll
        for (int n = 0; n < 4; ++n) prow[n * 32 + col] = psum[n];
    }
}

// ---- reduce: 128 blocks x 128 thr; block g sums 32 of the 4096 partial rows
__global__ __launch_bounds__(128) void reduceK(const float* __restrict__ partials,
                                               float* __restrict__ stage2) {
    int tid = threadIdx.x, g = blockIdx.x;
    size_t base = (size_t)g * 32 * 128;
    float s = 0.f;
#pragma unroll 8
    for (int r = 0; r < 32; ++r) s += partials[base + (size_t)r * 128 + tid];
    stage2[(size_t)g * 128 + tid] = s;
}

// ---- final tail: both batches in parallel (512 threads)
__global__ __launch_bounds__(512) void finalK(const float* __restrict__ stage2,
                                              const float* __restrict__ w3,
                                              const float* __restrict__ b3,
                                              const float* __restrict__ w4,
                                              const float* __restrict__ b4,
                                              const float* __restrict__ w5,
                                              const float* __restrict__ b5,
                                              float* __restrict__ out) {
    __shared__ float su[2][256], mid[2][256], o[2][256];
    int tid = threadIdx.x;
    int b = tid >> 8, c = tid & 255;
    int ch = c >> 7, cl = c & 127;
    // stage2 rows: g = bc*32 + sub, bc = b*2+ch
    const float* sb = stage2 + (size_t)(b * 2 + ch) * 32 * 128;
    float s = 0.f;
#pragma unroll 8
    for (int r = 0; r < 32; ++r) s += sb[(size_t)r * 128 + cl];
    su[b][c] = s;
    __syncthreads();
    float m = 262144.0f * b3[c];
    for (int k = 0; k < 256; ++k) m += su[b][k] * w3[k * 256 + c];
    mid[b][c] = m;
    __syncthreads();
    float ov = b4[c];
    for (int k = 0; k < 256; ++k) ov += mid[b][k] * w4[k * 256 + c];
    o[b][c] = fmaxf(ov, 0.f);
    __syncthreads();
    if (c < 64) {
        float r = b5[c];
        for (int k = 0; k < 256; ++k) r += o[b][k] * w5[k * 64 + c];
        out[b * 64 + c] = r;
    }
}

extern "C" void kernel_launch(void* const* d_in, const int* in_sizes, int n_in,
                              void* d_out, int out_size, void* d_ws, size_t ws_size,
                              hipStream_t stream) {
    const float* in = (const float*)d_in[0];
    const float* w1 = (const float*)d_in[1];
    const float* b1 = (const float*)d_in[2];
    const float* w2 = (const float*)d_in[3];
    const float* b2 = (const float*)d_in[4];
    const float* w3 = (const float*)d_in[5];
    const float* b3 = (const float*)d_in[6];
    const float* w4 = (const float*)d_in[7];
    const float* b4 = (const float*)d_in[8];
    const float* w5 = (const float*)d_in[9];
    const float* b5 = (const float*)d_in[10];
    float* out = (float*)d_out;

    char* ws = (char*)d_ws;
    float* hi       = (float*)(ws);                                    // 1 MB
    float* hcb      = (float*)(ws + (1u << 20));                       // 1 MB
    short* bfrag    = (short*)(ws + (2u << 20));                       // 128 KB
    float* partials = (float*)(ws + (2u << 20) + (256u << 10));        // 2 MB
    float* stage2   = (float*)(ws + (4u << 20) + (256u << 10));        // 64 KB

    prep<<<1280, 256, 0, stream>>>(in, w1, b1, w2, hi, hcb, bfrag);
    big<<<1024, 256, 0, stream>>>(hi, hcb, (const short8*)bfrag, b2, partials);
    reduceK<<<128, 128, 0, stream>>>(partials, stage2);
    finalK<<<1, 512, 0, stream>>>(stage2, w3, b3, w4, b4, w5, b5, out);
}